// Round 13
// baseline (643.147 us; speedup 1.0000x reference)
//
#include <hip/hip_runtime.h>
#include <math.h>

#define Nn 10000
#define En 160000
#define NF 5
#define EF 3
#define Hh 8
#define Cc 128
#define HC 1024
#define Gg 16

#define Mpad 10112   // 79 * 128

typedef __attribute__((ext_vector_type(8))) _Float16 half8;
typedef __attribute__((ext_vector_type(4))) float f32x4;

// ---------------- helpers ----------------

__device__ __forceinline__ void gl_lds16(const void* g, void* l) {
    __builtin_amdgcn_global_load_lds((const __attribute__((address_space(1))) void*)g,
                                     (__attribute__((address_space(3))) void*)l, 16, 0, 0);
}

__device__ __forceinline__ float elu_f(float v) {
    return (v > 0.f) ? v : expm1f(v);
}

// ---------------- preprocessing ----------------

__global__ void deg_sum_k(const int* __restrict__ dst, const float* __restrict__ ea,
                          int* __restrict__ cnt, float* __restrict__ sum_ea) {
    int e = blockIdx.x * 256 + threadIdx.x;
    if (e >= En) return;
    int d = dst[e];
    atomicAdd(&cnt[d], 1);
    atomicAdd(&sum_ea[d * 3 + 0], ea[e * 3 + 0]);
    atomicAdd(&sum_ea[d * 3 + 1], ea[e * 3 + 1]);
    atomicAdd(&sum_ea[d * 3 + 2], ea[e * 3 + 2]);
}

// scan (10 elems/thread + one block scan) + loop_attr divide + group bounds, fused
__global__ __launch_bounds__(1024) void scan_k(const int* __restrict__ cnt,
                                               int* __restrict__ rowptr,
                                               int* __restrict__ fillptr,
                                               float* __restrict__ loop_attr,
                                               const int* __restrict__ batch,
                                               int* __restrict__ gstart) {
    __shared__ int sh[1024];
    int tid = threadIdx.x;
    int base = tid * 10;
    int loc[10];
    int tsum = 0;
#pragma unroll
    for (int j = 0; j < 10; ++j) {
        int i = base + j;
        int v = 0;
        if (i < Nn) {
            v = cnt[i];
            float s = 1.0f / fmaxf((float)v, 1.0f);
            loop_attr[i * 3 + 0] *= s;
            loop_attr[i * 3 + 1] *= s;
            loop_attr[i * 3 + 2] *= s;
        }
        loc[j] = tsum;
        tsum += v;
    }
    sh[tid] = tsum;
    __syncthreads();
    for (int off = 1; off < 1024; off <<= 1) {
        int t = (tid >= off) ? sh[tid - off] : 0;
        __syncthreads();
        sh[tid] += t;
        __syncthreads();
    }
    int excl = sh[tid] - tsum;
#pragma unroll
    for (int j = 0; j < 10; ++j) {
        int i = base + j;
        if (i < Nn) {
            rowptr[i] = excl + loc[j];
            fillptr[i] = excl + loc[j];
        }
    }
    if (tid == 1023) rowptr[Nn] = sh[1023];
#pragma unroll
    for (int j = 0; j < 10; ++j) {
        int i = base + j;
        if (i < Nn) {
            int b = batch[i];
            if (i == 0) {
                for (int g = 0; g <= b; ++g) gstart[g] = 0;
            } else {
                int pb = batch[i - 1];
                for (int g = pb + 1; g <= b; ++g) gstart[g] = i;
            }
            if (i == Nn - 1) {
                for (int g = b + 1; g <= Gg; ++g) gstart[g] = Nn;
            }
        }
    }
}

// CSR fill: packed record per position: (ea0, ea1, ea2, src-as-float-bits)
__global__ void csr_fill_k(const int* __restrict__ src, const int* __restrict__ dst,
                           const float* __restrict__ ea, int* __restrict__ fillptr,
                           float4* __restrict__ eaP) {
    int e = blockIdx.x * 256 + threadIdx.x;
    if (e >= En) return;
    int d = dst[e];
    int pos = atomicAdd(&fillptr[d], 1);
    eaP[pos] = make_float4(ea[e * 3 + 0], ea[e * 3 + 1], ea[e * 3 + 2],
                           __int_as_float(src[e]));
}

// ---------------- weight prep (once, all layers) ----------------

__global__ void wae_all_k(const float* __restrict__ We1, const float* __restrict__ ae1,
                          const float* __restrict__ We2, const float* __restrict__ ae2,
                          const float* __restrict__ We3, const float* __restrict__ ae3,
                          const float* __restrict__ We4, const float* __restrict__ ae4,
                          float* __restrict__ w_ae_all) {
    int t = threadIdx.x;
    if (t >= 96) return;
    int l = t / 24, idx = t % 24;
    int f = idx >> 3, h = idx & 7;
    const float* We = (l == 0) ? We1 : (l == 1) ? We2 : (l == 2) ? We3 : We4;
    const float* ae = (l == 0) ? ae1 : (l == 1) ? ae2 : (l == 2) ? ae3 : ae4;
    float s = 0.f;
    for (int c = 0; c < Cc; ++c) s += We[f * HC + h * Cc + c] * ae[h * Cc + c];
    w_ae_all[l * 24 + f * 8 + h] = s;
}

__global__ __launch_bounds__(1024) void wsplit_all_k(const float* __restrict__ W2,
                                                     const float* __restrict__ W3,
                                                     const float* __restrict__ W4,
                                                     _Float16* __restrict__ Wt16) {
    __shared__ float tile[32][33];
    int z = blockIdx.z;
    const float* W = (z == 0) ? W2 : (z == 1) ? W3 : W4;
    int nb = blockIdx.x * 32, kb = blockIdx.y * 32;
    tile[threadIdx.y][threadIdx.x] = W[(size_t)(kb + threadIdx.y) * HC + nb + threadIdx.x];
    __syncthreads();
    float x = tile[threadIdx.x][threadIdx.y];   // W[kb+tx][nb+ty]
    int n = nb + threadIdx.y, k = kb + threadIdx.x;
    Wt16[(size_t)z * HC * HC + (size_t)n * HC + k] = (_Float16)x;
}

// ---------------- GEMMs (fused with a_src/a_dst head dots) ----------------

// layer-1 K=5 GEMM + per-head attention dots
__global__ void gemm_k5(const float* __restrict__ x, const float* __restrict__ Wm,
                        const float* __restrict__ a_s, const float* __restrict__ a_d,
                        _Float16* __restrict__ out16,
                        float* __restrict__ a_srcB, float* __restrict__ a_dstB) {
    int n = blockIdx.x;
    int tid = threadIdx.x;
    __shared__ float xr[8];
    __shared__ float vrow[HC];
    if (tid < NF) xr[tid] = x[n * NF + tid];
    __syncthreads();
    float x0 = xr[0], x1 = xr[1], x2 = xr[2], x3 = xr[3], x4 = xr[4];
    for (int j = tid; j < HC; j += 256) {
        float v = x0 * Wm[j] + x1 * Wm[HC + j] + x2 * Wm[2 * HC + j]
                + x3 * Wm[3 * HC + j] + x4 * Wm[4 * HC + j];
        out16[(size_t)n * HC + j] = (_Float16)v;
        vrow[j] = v;
    }
    __syncthreads();
    int w = tid >> 6, lane = tid & 63;
#pragma unroll
    for (int q = 0; q < 2; ++q) {
        int h = w * 2 + q;
        float v0 = vrow[h * Cc + lane], v1 = vrow[h * Cc + 64 + lane];
        float s1 = v0 * a_s[h * Cc + lane] + v1 * a_s[h * Cc + 64 + lane];
        float s2 = v0 * a_d[h * Cc + lane] + v1 * a_d[h * Cc + 64 + lane];
#pragma unroll
        for (int off = 32; off; off >>= 1) {
            s1 += __shfl_xor(s1, off);
            s2 += __shfl_xor(s2, off);
        }
        if (lane == 0) { a_srcB[n * 8 + h] = s1; a_dstB[n * 8 + h] = s2; }
    }
}

// fp16 MFMA GEMM (r7 / m97 structure: quad-contiguous staging, [row][32] LDS)
// + fused per-head a_src/a_dst dots. blockIdx.x == head since BN == Cc == 128.
__global__ __launch_bounds__(256) void gemm_mfma(const _Float16* __restrict__ A,
                                                 const _Float16* __restrict__ Bt,
                                                 const float* __restrict__ a_s,
                                                 const float* __restrict__ a_d,
                                                 _Float16* __restrict__ C16,
                                                 float* __restrict__ a_srcB,
                                                 float* __restrict__ a_dstB) {
    __shared__ _Float16 As[128 * 32];
    __shared__ _Float16 Bs[128 * 32];
    __shared__ float ps[128][2];
    __shared__ float pd[128][2];
    int tid = threadIdx.x;
    int wave = tid >> 6, lane = tid & 63;
    int wr = wave >> 1, wc = wave & 1;
    int row0 = blockIdx.y * 128;
    int col0 = blockIdx.x * 128;
    int h = blockIdx.x;   // head

    f32x4 acc[4][4];
#pragma unroll
    for (int i = 0; i < 4; ++i)
#pragma unroll
        for (int j = 0; j < 4; ++j) acc[i][j] = (f32x4){0.f, 0.f, 0.f, 0.f};

    int srow = lane >> 2;          // quad covers 64 contiguous bytes of one row
    int scol = (lane & 3) * 8;
    int fr = lane & 15;
    int fk = (lane >> 4) * 8;

    for (int kb = 0; kb < 1024; kb += 32) {
#pragma unroll
        for (int cc = 0; cc < 2; ++cc) {
            int c = wave + cc * 4;
            int r = c * 16 + srow;
            gl_lds16(A + (size_t)(row0 + r) * 1024 + kb + scol, &As[c * 512 + lane * 8]);
            gl_lds16(Bt + (size_t)(col0 + r) * 1024 + kb + scol, &Bs[c * 512 + lane * 8]);
        }
        __syncthreads();

        half8 af[4], bf[4];
#pragma unroll
        for (int i = 0; i < 4; ++i)
            af[i] = *(const half8*)&As[(wr * 64 + i * 16 + fr) * 32 + fk];
#pragma unroll
        for (int j = 0; j < 4; ++j)
            bf[j] = *(const half8*)&Bs[(wc * 64 + j * 16 + fr) * 32 + fk];
#pragma unroll
        for (int i = 0; i < 4; ++i)
#pragma unroll
            for (int j = 0; j < 4; ++j)
                acc[i][j] = __builtin_amdgcn_mfma_f32_16x16x32_f16(af[i], bf[j], acc[i][j],
                                                                   0, 0, 0);
        __syncthreads();
    }

    int cn = lane & 15, rq = (lane >> 4) * 4;
    // C write
#pragma unroll
    for (int i = 0; i < 4; ++i) {
        int rbase = row0 + wr * 64 + i * 16 + rq;
#pragma unroll
        for (int j = 0; j < 4; ++j) {
            int col = col0 + wc * 64 + j * 16 + cn;
#pragma unroll
            for (int r = 0; r < 4; ++r) {
                int row = rbase + r;
                if (row < Nn) C16[(size_t)row * HC + col] = (_Float16)acc[i][j][r];
            }
        }
    }
    // fused a_src/a_dst dots over this head's 128 channels
    float asv[4], adv[4];
#pragma unroll
    for (int j = 0; j < 4; ++j) {
        int c = wc * 64 + j * 16 + cn;
        asv[j] = a_s[h * Cc + c];
        adv[j] = a_d[h * Cc + c];
    }
#pragma unroll
    for (int i = 0; i < 4; ++i)
#pragma unroll
        for (int r = 0; r < 4; ++r) {
            float rs = acc[i][0][r] * asv[0] + acc[i][1][r] * asv[1]
                     + acc[i][2][r] * asv[2] + acc[i][3][r] * asv[3];
            float rd = acc[i][0][r] * adv[0] + acc[i][1][r] * adv[1]
                     + acc[i][2][r] * adv[2] + acc[i][3][r] * adv[3];
#pragma unroll
            for (int off = 1; off < 16; off <<= 1) {
                rs += __shfl_xor(rs, off);
                rd += __shfl_xor(rd, off);
            }
            if (cn == 0) {
                int rib = wr * 64 + i * 16 + rq + r;
                ps[rib][wc] = rs;
                pd[rib][wc] = rd;
            }
        }
    __syncthreads();
    if (tid < 128) {
        int row = row0 + tid;
        if (row < Nn) {
            a_srcB[row * 8 + h] = ps[tid][0] + ps[tid][1];
            a_dstB[row * 8 + h] = pd[tid][0] + pd[tid][1];
        }
    }
}

// ---------- fused attention aggregate (single pass, 8 waves/node: 4 edge x 2 channel) -------

// BLOCK = ONE NODE, 512 threads. wave = (es<<1)|cs: es = edge quarter (stride 4),
// cs = channel half. Lane owns 8 halfs at g0 = cs*512 + lane*8 (head = cs*4 + lane>>4).
// Softmax shift = aself (exact per node, Glorot-scale logits can't overflow fp32 exp).
// Unnormalized acc + per-head denominator s combine additively via conflict-free LDS
// (consecutive lanes -> consecutive 16B). Waves es=0 run the epilogue.
__global__ __launch_bounds__(512) void aggregate_k(const _Float16* __restrict__ xl16,
                                                   const float4* __restrict__ eaP,
                                                   const float* __restrict__ loop_attr,
                                                   const float* __restrict__ a_srcB,
                                                   const float* __restrict__ a_dstB,
                                                   const float* __restrict__ w_ae,
                                                   const int* __restrict__ rowptr,
                                                   const float* __restrict__ bias,
                                                   const float* __restrict__ lin_w,
                                                   _Float16* __restrict__ A2,
                                                   float* __restrict__ dnode,
                                                   int raw_mode) {
    __shared__ float4 cmb4[3][2][128];   // [es-1][j4][global lane] 12 KB, lane-contiguous
    __shared__ float cmbS[3][128];       // [es-1][global lane]
    __shared__ float hsum[128];          // layer-4 cross-cs head-sum handoff
    int wave = threadIdx.x >> 6;
    int lane = threadIdx.x & 63;
    int es = wave >> 1, cs = wave & 1;
    int gl = cs * 64 + lane;             // global lane 0..127
    int n = blockIdx.x;
    int beg = rowptr[n], end = rowptr[n + 1];
    int hd = cs * 4 + (lane >> 4);       // this lane's head
    int g0 = cs * 512 + lane * 8;        // first HC index owned by this lane

    float w0c = w_ae[hd], w1c = w_ae[8 + hd], w2c = w_ae[16 + hd];
    float adst_n = a_dstB[n * 8 + hd];
    float asrc_n = a_srcB[n * 8 + hd];
    float f0 = loop_attr[n * 3 + 0], f1 = loop_attr[n * 3 + 1], f2 = loop_attr[n * 3 + 2];
    float av = asrc_n + adst_n + f0 * w0c + f1 * w1c + f2 * w2c;
    float aself = (av > 0.f) ? av : 0.2f * av;   // softmax shift; self weight = 1

    float acc[8];
    float s;
    if (es == 0) {
        const _Float16* r = xl16 + (size_t)n * HC + g0;
        half8 r0 = *(const half8*)r;
#pragma unroll
        for (int j = 0; j < 8; ++j) acc[j] = (float)r0[j];
        s = 1.0f;
    } else {
#pragma unroll
        for (int j = 0; j < 8; ++j) acc[j] = 0.f;
        s = 0.0f;
    }

    for (int i0 = beg + es; i0 < end; i0 += 16) {
        bool v1 = (i0 + 4 < end), v2 = (i0 + 8 < end), v3 = (i0 + 12 < end);
        int i1 = v1 ? i0 + 4 : i0;
        int i2 = v2 ? i0 + 8 : i0;
        int i3 = v3 ? i0 + 12 : i0;
        float4 e0 = eaP[i0], e1 = eaP[i1], e2 = eaP[i2], e3 = eaP[i3];
        int s0 = __float_as_int(e0.w), s1 = __float_as_int(e1.w);
        int s2 = __float_as_int(e2.w), s3 = __float_as_int(e3.w);
        float as0 = a_srcB[s0 * 8 + hd], as1 = a_srcB[s1 * 8 + hd];
        float as2 = a_srcB[s2 * 8 + hd], as3 = a_srcB[s3 * 8 + hd];
        half8 q0 = *(const half8*)(xl16 + (size_t)s0 * HC + g0);
        half8 q1 = *(const half8*)(xl16 + (size_t)s1 * HC + g0);
        half8 q2 = *(const half8*)(xl16 + (size_t)s2 * HC + g0);
        half8 q3 = *(const half8*)(xl16 + (size_t)s3 * HC + g0);
        float al0 = as0 + adst_n + e0.x * w0c + e0.y * w1c + e0.z * w2c;
        float al1 = as1 + adst_n + e1.x * w0c + e1.y * w1c + e1.z * w2c;
        float al2 = as2 + adst_n + e2.x * w0c + e2.y * w1c + e2.z * w2c;
        float al3 = as3 + adst_n + e3.x * w0c + e3.y * w1c + e3.z * w2c;
        al0 = (al0 > 0.f) ? al0 : 0.2f * al0;
        al1 = (al1 > 0.f) ? al1 : 0.2f * al1;
        al2 = (al2 > 0.f) ? al2 : 0.2f * al2;
        al3 = (al3 > 0.f) ? al3 : 0.2f * al3;
        float u0 = __expf(al0 - aself);
        float u1 = v1 ? __expf(al1 - aself) : 0.f;
        float u2 = v2 ? __expf(al2 - aself) : 0.f;
        float u3 = v3 ? __expf(al3 - aself) : 0.f;
        s += u0 + u1 + u2 + u3;
#pragma unroll
        for (int j = 0; j < 8; ++j) {
            float t = acc[j];
            t = fmaf(u0, (float)q0[j], t);
            t = fmaf(u1, (float)q1[j], t);
            t = fmaf(u2, (float)q2[j], t);
            t = fmaf(u3, (float)q3[j], t);
            acc[j] = t;
        }
    }

    // additive combine across edge quarters (lane-contiguous stores: conflict-free)
    if (es != 0) {
        cmb4[es - 1][0][gl] = make_float4(acc[0], acc[1], acc[2], acc[3]);
        cmb4[es - 1][1][gl] = make_float4(acc[4], acc[5], acc[6], acc[7]);
        cmbS[es - 1][gl] = s;
    }
    __syncthreads();
    float inv = 0.f;
    if (es == 0) {
#pragma unroll
        for (int k = 0; k < 3; ++k) {
            s += cmbS[k][gl];
            float4 a0 = cmb4[k][0][gl];
            float4 a1 = cmb4[k][1][gl];
            acc[0] += a0.x; acc[1] += a0.y; acc[2] += a0.z; acc[3] += a0.w;
            acc[4] += a1.x; acc[5] += a1.y; acc[6] += a1.z; acc[7] += a1.w;
        }
        inv = 1.f / (s + 1e-16f);
    }

    if (!raw_mode) {
        if (es == 0) {
            half8 hv;
#pragma unroll
            for (int j = 0; j < 8; ++j)
                hv[j] = (_Float16)elu_f(fmaf(acc[j], inv, bias[g0 + j]));
            *(half8*)(A2 + (size_t)n * 1024 + g0) = hv;
        }
    } else {
        if (es == 0) {
            // normalize, then sum this wave's 4 heads per channel (lanes differ in bits 4..5)
#pragma unroll
            for (int j = 0; j < 8; ++j) acc[j] *= inv;
#pragma unroll
            for (int off = 16; off < 64; off <<= 1)
#pragma unroll
                for (int j = 0; j < 8; ++j) acc[j] += __shfl_xor(acc[j], off);
            if (cs == 1 && lane < 16) {
                *(float4*)&hsum[lane * 8] = make_float4(acc[0], acc[1], acc[2], acc[3]);
                *(float4*)&hsum[lane * 8 + 4] = make_float4(acc[4], acc[5], acc[6], acc[7]);
            }
        }
        __syncthreads();
        if (es == 0 && cs == 0) {
            int c0 = (lane & 15) * 8;
            float partial = 0.f;
#pragma unroll
            for (int j = 0; j < 8; ++j) {
                float tot = acc[j] + hsum[c0 + j];
                float v = elu_f(tot * 0.125f + bias[c0 + j]);
                partial = fmaf(v, lin_w[c0 + j], partial);
            }
#pragma unroll
            for (int off = 1; off < 16; off <<= 1) partial += __shfl_xor(partial, off);
            if (lane == 0) dnode[n] = partial;
        }
    }
}

// ---------------- pooling: reduce per-node scalars per group ----------------

__global__ __launch_bounds__(256) void pool_final_k(const float* __restrict__ dnode,
                                                    const int* __restrict__ gstart,
                                                    const float* __restrict__ lin_b,
                                                    float* __restrict__ out) {
    __shared__ float sh[256];
    int g = blockIdx.x;
    int tid = threadIdx.x;
    int s = gstart[g], e = gstart[g + 1];
    float acc = 0.f;
    for (int n = s + tid; n < e; n += 256) acc += dnode[n];
    sh[tid] = acc;
    __syncthreads();
    for (int off = 128; off; off >>= 1) {
        if (tid < off) sh[tid] += sh[tid + off];
        __syncthreads();
    }
    if (tid == 0) out[g] = sh[0] / fmaxf((float)(e - s), 1.f) + lin_b[0];
}

// ---------------- launch ----------------

extern "C" void kernel_launch(void* const* d_in, const int* in_sizes, int n_in,
                              void* d_out, int out_size, void* d_ws, size_t ws_size,
                              hipStream_t stream) {
    const float* x = (const float*)d_in[0];
    const int* ei = (const int*)d_in[1];
    const float* ea = (const float*)d_in[2];
    const int* batch = (const int*)d_in[3];
    const float *Wl[4], *Wel[4], *asl[4], *adl[4], *ael[4], *bl[4];
    for (int l = 0; l < 4; ++l) {
        Wl[l] = (const float*)d_in[4 + 6 * l];
        Wel[l] = (const float*)d_in[5 + 6 * l];
        asl[l] = (const float*)d_in[6 + 6 * l];
        adl[l] = (const float*)d_in[7 + 6 * l];
        ael[l] = (const float*)d_in[8 + 6 * l];
        bl[l] = (const float*)d_in[9 + 6 * l];
    }
    const float* lin_w = (const float*)d_in[28];
    const float* lin_b = (const float*)d_in[29];
    const int* srcA = ei;
    const int* dstA = ei + En;

    float* Wp = (float*)d_ws;
    size_t o = 0;
    _Float16* A2 = (_Float16*)(Wp + o); o += (size_t)Mpad * 512;         // elu acts fp16
    _Float16* Wt16 = (_Float16*)(Wp + o); o += (size_t)3 * HC * HC / 2;  // 3 fp16 W^T
    _Float16* xl16 = (_Float16*)(Wp + o); o += (size_t)Nn * HC / 2;      // xl fp16
    float4* eaP = (float4*)(Wp + o); o += (size_t)En * 4;                // packed (ea,src)
    float* loop_attr = Wp + o; o += Nn * 3;
    int* cnt = (int*)(Wp + o); o += Nn;
    int* rowptr = (int*)(Wp + o); o += Nn + 1;
    int* fillptr = (int*)(Wp + o); o += Nn;
    int* gstart = (int*)(Wp + o); o += Gg + 1;
    float* a_srcB = Wp + o; o += Nn * Hh;
    float* a_dstB = Wp + o; o += Nn * Hh;
    float* w_ae_all = Wp + o; o += 128;
    float* dnode = Wp + o; o += Nn;

    hipMemsetAsync(cnt, 0, Nn * sizeof(int), stream);
    hipMemsetAsync(loop_attr, 0, Nn * 3 * sizeof(float), stream);

    deg_sum_k<<<(En + 255) / 256, 256, 0, stream>>>(dstA, ea, cnt, loop_attr);
    scan_k<<<1, 1024, 0, stream>>>(cnt, rowptr, fillptr, loop_attr, batch, gstart);
    csr_fill_k<<<(En + 255) / 256, 256, 0, stream>>>(srcA, dstA, ea, fillptr, eaP);
    wae_all_k<<<1, 128, 0, stream>>>(Wel[0], ael[0], Wel[1], ael[1], Wel[2], ael[2],
                                     Wel[3], ael[3], w_ae_all);
    wsplit_all_k<<<dim3(32, 32, 3), dim3(32, 32), 0, stream>>>(Wl[1], Wl[2], Wl[3], Wt16);

    for (int l = 0; l < 4; ++l) {
        if (l == 0)
            gemm_k5<<<Nn, 256, 0, stream>>>(x, Wl[0], asl[0], adl[0], xl16, a_srcB, a_dstB);
        else
            gemm_mfma<<<dim3(HC / 128, Mpad / 128), 256, 0, stream>>>(
                A2, Wt16 + (size_t)(l - 1) * HC * HC, asl[l], adl[l], xl16, a_srcB, a_dstB);
        aggregate_k<<<Nn, 512, 0, stream>>>(xl16, eaP, loop_attr, a_srcB,
                                            a_dstB, w_ae_all + l * 24, rowptr,
                                            bl[l], lin_w, A2, dnode,
                                            (l == 3) ? 1 : 0);
    }
    pool_final_k<<<Gg, 256, 0, stream>>>(dnode, gstart, lin_b, (float*)d_out);
}

// Round 14
// 592.190 us; speedup vs baseline: 1.0860x; 1.0860x over previous
//
#include <hip/hip_runtime.h>
#include <math.h>

#define Nn 10000
#define En 160000
#define NF 5
#define EF 3
#define Hh 8
#define Cc 128
#define HC 1024
#define Gg 16

#define Mpad 10112   // 79 * 128

typedef __attribute__((ext_vector_type(8))) _Float16 half8;
typedef __attribute__((ext_vector_type(4))) float f32x4;

// ---------------- helpers ----------------

__device__ __forceinline__ void gl_lds16(const void* g, void* l) {
    __builtin_amdgcn_global_load_lds((const __attribute__((address_space(1))) void*)g,
                                     (__attribute__((address_space(3))) void*)l, 16, 0, 0);
}

__device__ __forceinline__ float elu_f(float v) {
    return (v > 0.f) ? v : expm1f(v);
}

// ---------------- preprocessing ----------------

__global__ void deg_sum_k(const int* __restrict__ dst, const float* __restrict__ ea,
                          int* __restrict__ cnt, float* __restrict__ sum_ea) {
    int e = blockIdx.x * 256 + threadIdx.x;
    if (e >= En) return;
    int d = dst[e];
    atomicAdd(&cnt[d], 1);
    atomicAdd(&sum_ea[d * 3 + 0], ea[e * 3 + 0]);
    atomicAdd(&sum_ea[d * 3 + 1], ea[e * 3 + 1]);
    atomicAdd(&sum_ea[d * 3 + 2], ea[e * 3 + 2]);
}

// scan (10 elems/thread + one block scan) + loop_attr divide + group bounds, fused
__global__ __launch_bounds__(1024) void scan_k(const int* __restrict__ cnt,
                                               int* __restrict__ rowptr,
                                               int* __restrict__ fillptr,
                                               float* __restrict__ loop_attr,
                                               const int* __restrict__ batch,
                                               int* __restrict__ gstart) {
    __shared__ int sh[1024];
    int tid = threadIdx.x;
    int base = tid * 10;
    int loc[10];
    int tsum = 0;
#pragma unroll
    for (int j = 0; j < 10; ++j) {
        int i = base + j;
        int v = 0;
        if (i < Nn) {
            v = cnt[i];
            float s = 1.0f / fmaxf((float)v, 1.0f);
            loop_attr[i * 3 + 0] *= s;
            loop_attr[i * 3 + 1] *= s;
            loop_attr[i * 3 + 2] *= s;
        }
        loc[j] = tsum;
        tsum += v;
    }
    sh[tid] = tsum;
    __syncthreads();
    for (int off = 1; off < 1024; off <<= 1) {
        int t = (tid >= off) ? sh[tid - off] : 0;
        __syncthreads();
        sh[tid] += t;
        __syncthreads();
    }
    int excl = sh[tid] - tsum;
#pragma unroll
    for (int j = 0; j < 10; ++j) {
        int i = base + j;
        if (i < Nn) {
            rowptr[i] = excl + loc[j];
            fillptr[i] = excl + loc[j];
        }
    }
    if (tid == 1023) rowptr[Nn] = sh[1023];
#pragma unroll
    for (int j = 0; j < 10; ++j) {
        int i = base + j;
        if (i < Nn) {
            int b = batch[i];
            if (i == 0) {
                for (int g = 0; g <= b; ++g) gstart[g] = 0;
            } else {
                int pb = batch[i - 1];
                for (int g = pb + 1; g <= b; ++g) gstart[g] = i;
            }
            if (i == Nn - 1) {
                for (int g = b + 1; g <= Gg; ++g) gstart[g] = Nn;
            }
        }
    }
}

// CSR fill: packed record per position: (ea0, ea1, ea2, src-as-float-bits)
__global__ void csr_fill_k(const int* __restrict__ src, const int* __restrict__ dst,
                           const float* __restrict__ ea, int* __restrict__ fillptr,
                           float4* __restrict__ eaP) {
    int e = blockIdx.x * 256 + threadIdx.x;
    if (e >= En) return;
    int d = dst[e];
    int pos = atomicAdd(&fillptr[d], 1);
    eaP[pos] = make_float4(ea[e * 3 + 0], ea[e * 3 + 1], ea[e * 3 + 2],
                           __int_as_float(src[e]));
}

// ---------------- weight prep (once, all layers) ----------------

__global__ void wae_all_k(const float* __restrict__ We1, const float* __restrict__ ae1,
                          const float* __restrict__ We2, const float* __restrict__ ae2,
                          const float* __restrict__ We3, const float* __restrict__ ae3,
                          const float* __restrict__ We4, const float* __restrict__ ae4,
                          float* __restrict__ w_ae_all) {
    int t = threadIdx.x;
    if (t >= 96) return;
    int l = t / 24, idx = t % 24;
    int f = idx >> 3, h = idx & 7;
    const float* We = (l == 0) ? We1 : (l == 1) ? We2 : (l == 2) ? We3 : We4;
    const float* ae = (l == 0) ? ae1 : (l == 1) ? ae2 : (l == 2) ? ae3 : ae4;
    float s = 0.f;
    for (int c = 0; c < Cc; ++c) s += We[f * HC + h * Cc + c] * ae[h * Cc + c];
    w_ae_all[l * 24 + f * 8 + h] = s;
}

__global__ __launch_bounds__(1024) void wsplit_all_k(const float* __restrict__ W2,
                                                     const float* __restrict__ W3,
                                                     const float* __restrict__ W4,
                                                     _Float16* __restrict__ Wt16) {
    __shared__ float tile[32][33];
    int z = blockIdx.z;
    const float* W = (z == 0) ? W2 : (z == 1) ? W3 : W4;
    int nb = blockIdx.x * 32, kb = blockIdx.y * 32;
    tile[threadIdx.y][threadIdx.x] = W[(size_t)(kb + threadIdx.y) * HC + nb + threadIdx.x];
    __syncthreads();
    float x = tile[threadIdx.x][threadIdx.y];   // W[kb+tx][nb+ty]
    int n = nb + threadIdx.y, k = kb + threadIdx.x;
    Wt16[(size_t)z * HC * HC + (size_t)n * HC + k] = (_Float16)x;
}

// ---------------- GEMMs (fused with a_src/a_dst head dots) ----------------

// layer-1 K=5 GEMM + per-head attention dots
__global__ void gemm_k5(const float* __restrict__ x, const float* __restrict__ Wm,
                        const float* __restrict__ a_s, const float* __restrict__ a_d,
                        _Float16* __restrict__ out16,
                        float* __restrict__ a_srcB, float* __restrict__ a_dstB) {
    int n = blockIdx.x;
    int tid = threadIdx.x;
    __shared__ float xr[8];
    __shared__ float vrow[HC];
    if (tid < NF) xr[tid] = x[n * NF + tid];
    __syncthreads();
    float x0 = xr[0], x1 = xr[1], x2 = xr[2], x3 = xr[3], x4 = xr[4];
    for (int j = tid; j < HC; j += 256) {
        float v = x0 * Wm[j] + x1 * Wm[HC + j] + x2 * Wm[2 * HC + j]
                + x3 * Wm[3 * HC + j] + x4 * Wm[4 * HC + j];
        out16[(size_t)n * HC + j] = (_Float16)v;
        vrow[j] = v;
    }
    __syncthreads();
    int w = tid >> 6, lane = tid & 63;
#pragma unroll
    for (int q = 0; q < 2; ++q) {
        int h = w * 2 + q;
        float v0 = vrow[h * Cc + lane], v1 = vrow[h * Cc + 64 + lane];
        float s1 = v0 * a_s[h * Cc + lane] + v1 * a_s[h * Cc + 64 + lane];
        float s2 = v0 * a_d[h * Cc + lane] + v1 * a_d[h * Cc + 64 + lane];
#pragma unroll
        for (int off = 32; off; off >>= 1) {
            s1 += __shfl_xor(s1, off);
            s2 += __shfl_xor(s2, off);
        }
        if (lane == 0) { a_srcB[n * 8 + h] = s1; a_dstB[n * 8 + h] = s2; }
    }
}

// fp16 MFMA GEMM (r7 / m97 structure: quad-contiguous staging, [row][32] LDS)
// + fused per-head a_src/a_dst dots. blockIdx.x == head since BN == Cc == 128.
__global__ __launch_bounds__(256) void gemm_mfma(const _Float16* __restrict__ A,
                                                 const _Float16* __restrict__ Bt,
                                                 const float* __restrict__ a_s,
                                                 const float* __restrict__ a_d,
                                                 _Float16* __restrict__ C16,
                                                 float* __restrict__ a_srcB,
                                                 float* __restrict__ a_dstB) {
    __shared__ _Float16 As[128 * 32];
    __shared__ _Float16 Bs[128 * 32];
    __shared__ float ps[128][2];
    __shared__ float pd[128][2];
    int tid = threadIdx.x;
    int wave = tid >> 6, lane = tid & 63;
    int wr = wave >> 1, wc = wave & 1;
    int row0 = blockIdx.y * 128;
    int col0 = blockIdx.x * 128;
    int h = blockIdx.x;   // head

    f32x4 acc[4][4];
#pragma unroll
    for (int i = 0; i < 4; ++i)
#pragma unroll
        for (int j = 0; j < 4; ++j) acc[i][j] = (f32x4){0.f, 0.f, 0.f, 0.f};

    int srow = lane >> 2;          // quad covers 64 contiguous bytes of one row
    int scol = (lane & 3) * 8;
    int fr = lane & 15;
    int fk = (lane >> 4) * 8;

    for (int kb = 0; kb < 1024; kb += 32) {
#pragma unroll
        for (int cc = 0; cc < 2; ++cc) {
            int c = wave + cc * 4;
            int r = c * 16 + srow;
            gl_lds16(A + (size_t)(row0 + r) * 1024 + kb + scol, &As[c * 512 + lane * 8]);
            gl_lds16(Bt + (size_t)(col0 + r) * 1024 + kb + scol, &Bs[c * 512 + lane * 8]);
        }
        __syncthreads();

        half8 af[4], bf[4];
#pragma unroll
        for (int i = 0; i < 4; ++i)
            af[i] = *(const half8*)&As[(wr * 64 + i * 16 + fr) * 32 + fk];
#pragma unroll
        for (int j = 0; j < 4; ++j)
            bf[j] = *(const half8*)&Bs[(wc * 64 + j * 16 + fr) * 32 + fk];
#pragma unroll
        for (int i = 0; i < 4; ++i)
#pragma unroll
            for (int j = 0; j < 4; ++j)
                acc[i][j] = __builtin_amdgcn_mfma_f32_16x16x32_f16(af[i], bf[j], acc[i][j],
                                                                   0, 0, 0);
        __syncthreads();
    }

    int cn = lane & 15, rq = (lane >> 4) * 4;
    // C write
#pragma unroll
    for (int i = 0; i < 4; ++i) {
        int rbase = row0 + wr * 64 + i * 16 + rq;
#pragma unroll
        for (int j = 0; j < 4; ++j) {
            int col = col0 + wc * 64 + j * 16 + cn;
#pragma unroll
            for (int r = 0; r < 4; ++r) {
                int row = rbase + r;
                if (row < Nn) C16[(size_t)row * HC + col] = (_Float16)acc[i][j][r];
            }
        }
    }
    // fused a_src/a_dst dots over this head's 128 channels
    float asv[4], adv[4];
#pragma unroll
    for (int j = 0; j < 4; ++j) {
        int c = wc * 64 + j * 16 + cn;
        asv[j] = a_s[h * Cc + c];
        adv[j] = a_d[h * Cc + c];
    }
#pragma unroll
    for (int i = 0; i < 4; ++i)
#pragma unroll
        for (int r = 0; r < 4; ++r) {
            float rs = acc[i][0][r] * asv[0] + acc[i][1][r] * asv[1]
                     + acc[i][2][r] * asv[2] + acc[i][3][r] * asv[3];
            float rd = acc[i][0][r] * adv[0] + acc[i][1][r] * adv[1]
                     + acc[i][2][r] * adv[2] + acc[i][3][r] * adv[3];
#pragma unroll
            for (int off = 1; off < 16; off <<= 1) {
                rs += __shfl_xor(rs, off);
                rd += __shfl_xor(rd, off);
            }
            if (cn == 0) {
                int rib = wr * 64 + i * 16 + rq + r;
                ps[rib][wc] = rs;
                pd[rib][wc] = rd;
            }
        }
    __syncthreads();
    if (tid < 128) {
        int row = row0 + tid;
        if (row < Nn) {
            a_srcB[row * 8 + h] = ps[tid][0] + ps[tid][1];
            a_dstB[row * 8 + h] = pd[tid][0] + pd[tid][1];
        }
    }
}

// ---------------- fused attention aggregate (single pass, 4 waves/node) ----------------

// BLOCK = ONE NODE, 4 waves (r12 structure). Softmax shift = aself (exact per-node;
// Glorot-scale logits can't overflow fp32 exp). Each sub-wave gathers edges beg+sub::4
// (4-unrolled => stride 16), accumulating UNNORMALIZED acc + denominator s.
// Additive combine via CONFLICT-FREE LDS (float4 indexed [j4][lane]: consecutive
// lanes -> consecutive 16B); wave 0 normalizes + epilogue.
// mode 0: out = elu(agg+bias) -> fp16 into A2 (next GEMM input)
// mode 1: head-mean+bias+elu, dot with lin_w -> dnode[n] (scalar)
__global__ __launch_bounds__(256) void aggregate_k(const _Float16* __restrict__ xl16,
                                                   const float4* __restrict__ eaP,
                                                   const float* __restrict__ loop_attr,
                                                   const float* __restrict__ a_srcB,
                                                   const float* __restrict__ a_dstB,
                                                   const float* __restrict__ w_ae,
                                                   const int* __restrict__ rowptr,
                                                   const float* __restrict__ bias,
                                                   const float* __restrict__ lin_w,
                                                   _Float16* __restrict__ A2,
                                                   float* __restrict__ dnode,
                                                   int raw_mode) {
    __shared__ float4 cmb4[3][4][64];   // [sub-1][j4][lane]: lane-contiguous, conflict-free
    __shared__ float cmbS[3][64];
    int sub = threadIdx.x >> 6;
    int lane = threadIdx.x & 63;
    int n = blockIdx.x;
    int beg = rowptr[n], end = rowptr[n + 1];
    int hc = lane >> 3;     // this lane's head

    float w0c = w_ae[hc], w1c = w_ae[8 + hc], w2c = w_ae[16 + hc];
    float adst_n = a_dstB[n * 8 + hc];
    float asrc_n = a_srcB[n * 8 + hc];
    float f0 = loop_attr[n * 3 + 0], f1 = loop_attr[n * 3 + 1], f2 = loop_attr[n * 3 + 2];
    float av = asrc_n + adst_n + f0 * w0c + f1 * w1c + f2 * w2c;
    float aself = (av > 0.f) ? av : 0.2f * av;   // softmax shift; self weight = 1

    float acc[16];
    float s;
    int loff = lane * 16;
    if (sub == 0) {
        // self term (weight exp(0) = 1)
        const _Float16* r = xl16 + (size_t)n * HC + loff;
        half8 r0 = *(const half8*)r;
        half8 r1 = *(const half8*)(r + 8);
#pragma unroll
        for (int j = 0; j < 8; ++j) {
            acc[j] = (float)r0[j];
            acc[8 + j] = (float)r1[j];
        }
        s = 1.0f;
    } else {
#pragma unroll
        for (int j = 0; j < 16; ++j) acc[j] = 0.f;
        s = 0.0f;
    }

    for (int i0 = beg + sub; i0 < end; i0 += 16) {
        bool v1 = (i0 + 4 < end), v2 = (i0 + 8 < end), v3 = (i0 + 12 < end);
        int i1 = v1 ? i0 + 4 : i0;
        int i2 = v2 ? i0 + 8 : i0;
        int i3 = v3 ? i0 + 12 : i0;
        float4 e0 = eaP[i0], e1 = eaP[i1], e2 = eaP[i2], e3 = eaP[i3];
        int s0 = __float_as_int(e0.w), s1 = __float_as_int(e1.w);
        int s2 = __float_as_int(e2.w), s3 = __float_as_int(e3.w);
        float as0 = a_srcB[s0 * 8 + hc], as1 = a_srcB[s1 * 8 + hc];
        float as2 = a_srcB[s2 * 8 + hc], as3 = a_srcB[s3 * 8 + hc];
        const _Float16* p0 = xl16 + (size_t)s0 * HC + loff;
        const _Float16* p1 = xl16 + (size_t)s1 * HC + loff;
        const _Float16* p2 = xl16 + (size_t)s2 * HC + loff;
        const _Float16* p3 = xl16 + (size_t)s3 * HC + loff;
        half8 q0a = *(const half8*)p0, q0b = *(const half8*)(p0 + 8);
        half8 q1a = *(const half8*)p1, q1b = *(const half8*)(p1 + 8);
        half8 q2a = *(const half8*)p2, q2b = *(const half8*)(p2 + 8);
        half8 q3a = *(const half8*)p3, q3b = *(const half8*)(p3 + 8);
        float al0 = as0 + adst_n + e0.x * w0c + e0.y * w1c + e0.z * w2c;
        float al1 = as1 + adst_n + e1.x * w0c + e1.y * w1c + e1.z * w2c;
        float al2 = as2 + adst_n + e2.x * w0c + e2.y * w1c + e2.z * w2c;
        float al3 = as3 + adst_n + e3.x * w0c + e3.y * w1c + e3.z * w2c;
        al0 = (al0 > 0.f) ? al0 : 0.2f * al0;
        al1 = (al1 > 0.f) ? al1 : 0.2f * al1;
        al2 = (al2 > 0.f) ? al2 : 0.2f * al2;
        al3 = (al3 > 0.f) ? al3 : 0.2f * al3;
        float u0 = __expf(al0 - aself);
        float u1 = v1 ? __expf(al1 - aself) : 0.f;
        float u2 = v2 ? __expf(al2 - aself) : 0.f;
        float u3 = v3 ? __expf(al3 - aself) : 0.f;
        s += u0 + u1 + u2 + u3;
#pragma unroll
        for (int j = 0; j < 8; ++j) {
            float t0 = acc[j], t1 = acc[8 + j];
            t0 = fmaf(u0, (float)q0a[j], t0);  t1 = fmaf(u0, (float)q0b[j], t1);
            t0 = fmaf(u1, (float)q1a[j], t0);  t1 = fmaf(u1, (float)q1b[j], t1);
            t0 = fmaf(u2, (float)q2a[j], t0);  t1 = fmaf(u2, (float)q2b[j], t1);
            t0 = fmaf(u3, (float)q3a[j], t0);  t1 = fmaf(u3, (float)q3b[j], t1);
            acc[j] = t0; acc[8 + j] = t1;
        }
    }

    // additive combine across the 4 sub-waves (conflict-free stores/loads)
    if (sub != 0) {
#pragma unroll
        for (int j = 0; j < 4; ++j)
            cmb4[sub - 1][j][lane] = make_float4(acc[j * 4 + 0], acc[j * 4 + 1],
                                                 acc[j * 4 + 2], acc[j * 4 + 3]);
        cmbS[sub - 1][lane] = s;
    }
    __syncthreads();
    if (sub != 0) return;

#pragma unroll
    for (int k = 0; k < 3; ++k) {
        s += cmbS[k][lane];
#pragma unroll
        for (int j = 0; j < 4; ++j) {
            float4 c4 = cmb4[k][j][lane];
            acc[j * 4 + 0] += c4.x;
            acc[j * 4 + 1] += c4.y;
            acc[j * 4 + 2] += c4.z;
            acc[j * 4 + 3] += c4.w;
        }
    }
    float inv = 1.f / (s + 1e-16f);

    if (!raw_mode) {
        int ch = loff;
        half8 hv0, hv1;
#pragma unroll
        for (int j = 0; j < 8; ++j) {
            hv0[j] = (_Float16)elu_f(fmaf(acc[j], inv, bias[ch + j]));
            hv1[j] = (_Float16)elu_f(fmaf(acc[8 + j], inv, bias[ch + 8 + j]));
        }
        _Float16* p = A2 + (size_t)n * 1024 + ch;
        *(half8*)p = hv0;
        *(half8*)(p + 8) = hv1;
    } else {
        // normalize, then head-mean over the 8 lanes sharing lane&7
#pragma unroll
        for (int j = 0; j < 16; ++j) acc[j] *= inv;
#pragma unroll
        for (int off = 8; off < 64; off <<= 1)
#pragma unroll
            for (int j = 0; j < 16; ++j) acc[j] += __shfl_xor(acc[j], off);
        int c0 = (lane & 7) * 16;
        float partial = 0.f;
#pragma unroll
        for (int j = 0; j < 16; ++j) {
            float v = elu_f(acc[j] * 0.125f + bias[c0 + j]);
            partial = fmaf(v, lin_w[c0 + j], partial);
        }
#pragma unroll
        for (int off = 1; off < 8; off <<= 1) partial += __shfl_xor(partial, off);
        if (lane == 0) dnode[n] = partial;
    }
}

// ---------------- pooling: reduce per-node scalars per group ----------------

__global__ __launch_bounds__(256) void pool_final_k(const float* __restrict__ dnode,
                                                    const int* __restrict__ gstart,
                                                    const float* __restrict__ lin_b,
                                                    float* __restrict__ out) {
    __shared__ float sh[256];
    int g = blockIdx.x;
    int tid = threadIdx.x;
    int s = gstart[g], e = gstart[g + 1];
    float acc = 0.f;
    for (int n = s + tid; n < e; n += 256) acc += dnode[n];
    sh[tid] = acc;
    __syncthreads();
    for (int off = 128; off; off >>= 1) {
        if (tid < off) sh[tid] += sh[tid + off];
        __syncthreads();
    }
    if (tid == 0) out[g] = sh[0] / fmaxf((float)(e - s), 1.f) + lin_b[0];
}

// ---------------- launch ----------------

extern "C" void kernel_launch(void* const* d_in, const int* in_sizes, int n_in,
                              void* d_out, int out_size, void* d_ws, size_t ws_size,
                              hipStream_t stream) {
    const float* x = (const float*)d_in[0];
    const int* ei = (const int*)d_in[1];
    const float* ea = (const float*)d_in[2];
    const int* batch = (const int*)d_in[3];
    const float *Wl[4], *Wel[4], *asl[4], *adl[4], *ael[4], *bl[4];
    for (int l = 0; l < 4; ++l) {
        Wl[l] = (const float*)d_in[4 + 6 * l];
        Wel[l] = (const float*)d_in[5 + 6 * l];
        asl[l] = (const float*)d_in[6 + 6 * l];
        adl[l] = (const float*)d_in[7 + 6 * l];
        ael[l] = (const float*)d_in[8 + 6 * l];
        bl[l] = (const float*)d_in[9 + 6 * l];
    }
    const float* lin_w = (const float*)d_in[28];
    const float* lin_b = (const float*)d_in[29];
    const int* srcA = ei;
    const int* dstA = ei + En;

    float* Wp = (float*)d_ws;
    size_t o = 0;
    _Float16* A2 = (_Float16*)(Wp + o); o += (size_t)Mpad * 512;         // elu acts fp16
    _Float16* Wt16 = (_Float16*)(Wp + o); o += (size_t)3 * HC * HC / 2;  // 3 fp16 W^T
    _Float16* xl16 = (_Float16*)(Wp + o); o += (size_t)Nn * HC / 2;      // xl fp16
    float4* eaP = (float4*)(Wp + o); o += (size_t)En * 4;                // packed (ea,src)
    float* loop_attr = Wp + o; o += Nn * 3;
    int* cnt = (int*)(Wp + o); o += Nn;
    int* rowptr = (int*)(Wp + o); o += Nn + 1;
    int* fillptr = (int*)(Wp + o); o += Nn;
    int* gstart = (int*)(Wp + o); o += Gg + 1;
    float* a_srcB = Wp + o; o += Nn * Hh;
    float* a_dstB = Wp + o; o += Nn * Hh;
    float* w_ae_all = Wp + o; o += 128;
    float* dnode = Wp + o; o += Nn;

    hipMemsetAsync(cnt, 0, Nn * sizeof(int), stream);
    hipMemsetAsync(loop_attr, 0, Nn * 3 * sizeof(float), stream);

    deg_sum_k<<<(En + 255) / 256, 256, 0, stream>>>(dstA, ea, cnt, loop_attr);
    scan_k<<<1, 1024, 0, stream>>>(cnt, rowptr, fillptr, loop_attr, batch, gstart);
    csr_fill_k<<<(En + 255) / 256, 256, 0, stream>>>(srcA, dstA, ea, fillptr, eaP);
    wae_all_k<<<1, 128, 0, stream>>>(Wel[0], ael[0], Wel[1], ael[1], Wel[2], ael[2],
                                     Wel[3], ael[3], w_ae_all);
    wsplit_all_k<<<dim3(32, 32, 3), dim3(32, 32), 0, stream>>>(Wl[1], Wl[2], Wl[3], Wt16);

    for (int l = 0; l < 4; ++l) {
        if (l == 0)
            gemm_k5<<<Nn, 256, 0, stream>>>(x, Wl[0], asl[0], adl[0], xl16, a_srcB, a_dstB);
        else
            gemm_mfma<<<dim3(HC / 128, Mpad / 128), 256, 0, stream>>>(
                A2, Wt16 + (size_t)(l - 1) * HC * HC, asl[l], adl[l], xl16, a_srcB, a_dstB);
        aggregate_k<<<Nn, 256, 0, stream>>>(xl16, eaP, loop_attr, a_srcB,
                                            a_dstB, w_ae_all + l * 24, rowptr,
                                            bl[l], lin_w, A2, dnode,
                                            (l == 3) ? 1 : 0);
    }
    pool_final_k<<<Gg, 256, 0, stream>>>(dnode, gstart, lin_b, (float*)d_out);
}

// Round 15
// 563.903 us; speedup vs baseline: 1.1405x; 1.0502x over previous
//
#include <hip/hip_runtime.h>
#include <math.h>

#define Nn 10000
#define En 160000
#define NF 5
#define EF 3
#define Hh 8
#define Cc 128
#define HC 1024
#define Gg 16

#define Mpad 10112   // 79 * 128

typedef __attribute__((ext_vector_type(8))) _Float16 half8;
typedef __attribute__((ext_vector_type(4))) float f32x4;

// ---------------- helpers ----------------

__device__ __forceinline__ void gl_lds16(const void* g, void* l) {
    __builtin_amdgcn_global_load_lds((const __attribute__((address_space(1))) void*)g,
                                     (__attribute__((address_space(3))) void*)l, 16, 0, 0);
}

__device__ __forceinline__ float elu_f(float v) {
    return (v > 0.f) ? v : expm1f(v);
}

// ---------------- preprocessing ----------------

__global__ void deg_sum_k(const int* __restrict__ dst, const float* __restrict__ ea,
                          int* __restrict__ cnt, float* __restrict__ sum_ea) {
    int e = blockIdx.x * 256 + threadIdx.x;
    if (e >= En) return;
    int d = dst[e];
    atomicAdd(&cnt[d], 1);
    atomicAdd(&sum_ea[d * 3 + 0], ea[e * 3 + 0]);
    atomicAdd(&sum_ea[d * 3 + 1], ea[e * 3 + 1]);
    atomicAdd(&sum_ea[d * 3 + 2], ea[e * 3 + 2]);
}

// scan (10 elems/thread + one block scan) + loop_attr divide + group bounds, fused
__global__ __launch_bounds__(1024) void scan_k(const int* __restrict__ cnt,
                                               int* __restrict__ rowptr,
                                               int* __restrict__ fillptr,
                                               float* __restrict__ loop_attr,
                                               const int* __restrict__ batch,
                                               int* __restrict__ gstart) {
    __shared__ int sh[1024];
    int tid = threadIdx.x;
    int base = tid * 10;
    int loc[10];
    int tsum = 0;
#pragma unroll
    for (int j = 0; j < 10; ++j) {
        int i = base + j;
        int v = 0;
        if (i < Nn) {
            v = cnt[i];
            float s = 1.0f / fmaxf((float)v, 1.0f);
            loop_attr[i * 3 + 0] *= s;
            loop_attr[i * 3 + 1] *= s;
            loop_attr[i * 3 + 2] *= s;
        }
        loc[j] = tsum;
        tsum += v;
    }
    sh[tid] = tsum;
    __syncthreads();
    for (int off = 1; off < 1024; off <<= 1) {
        int t = (tid >= off) ? sh[tid - off] : 0;
        __syncthreads();
        sh[tid] += t;
        __syncthreads();
    }
    int excl = sh[tid] - tsum;
#pragma unroll
    for (int j = 0; j < 10; ++j) {
        int i = base + j;
        if (i < Nn) {
            rowptr[i] = excl + loc[j];
            fillptr[i] = excl + loc[j];
        }
    }
    if (tid == 1023) rowptr[Nn] = sh[1023];
#pragma unroll
    for (int j = 0; j < 10; ++j) {
        int i = base + j;
        if (i < Nn) {
            int b = batch[i];
            if (i == 0) {
                for (int g = 0; g <= b; ++g) gstart[g] = 0;
            } else {
                int pb = batch[i - 1];
                for (int g = pb + 1; g <= b; ++g) gstart[g] = i;
            }
            if (i == Nn - 1) {
                for (int g = b + 1; g <= Gg; ++g) gstart[g] = Nn;
            }
        }
    }
}

// CSR fill: packed record per position: (ea0, ea1, ea2, src-as-float-bits)
__global__ void csr_fill_k(const int* __restrict__ src, const int* __restrict__ dst,
                           const float* __restrict__ ea, int* __restrict__ fillptr,
                           float4* __restrict__ eaP) {
    int e = blockIdx.x * 256 + threadIdx.x;
    if (e >= En) return;
    int d = dst[e];
    int pos = atomicAdd(&fillptr[d], 1);
    eaP[pos] = make_float4(ea[e * 3 + 0], ea[e * 3 + 1], ea[e * 3 + 2],
                           __int_as_float(src[e]));
}

// ---------------- weight prep (once, all layers) ----------------

__global__ void wae_all_k(const float* __restrict__ We1, const float* __restrict__ ae1,
                          const float* __restrict__ We2, const float* __restrict__ ae2,
                          const float* __restrict__ We3, const float* __restrict__ ae3,
                          const float* __restrict__ We4, const float* __restrict__ ae4,
                          float* __restrict__ w_ae_all) {
    int t = threadIdx.x;
    if (t >= 96) return;
    int l = t / 24, idx = t % 24;
    int f = idx >> 3, h = idx & 7;
    const float* We = (l == 0) ? We1 : (l == 1) ? We2 : (l == 2) ? We3 : We4;
    const float* ae = (l == 0) ? ae1 : (l == 1) ? ae2 : (l == 2) ? ae3 : ae4;
    float s = 0.f;
    for (int c = 0; c < Cc; ++c) s += We[f * HC + h * Cc + c] * ae[h * Cc + c];
    w_ae_all[l * 24 + f * 8 + h] = s;
}

__global__ __launch_bounds__(1024) void wsplit_all_k(const float* __restrict__ W2,
                                                     const float* __restrict__ W3,
                                                     const float* __restrict__ W4,
                                                     _Float16* __restrict__ Wt16) {
    __shared__ float tile[32][33];
    int z = blockIdx.z;
    const float* W = (z == 0) ? W2 : (z == 1) ? W3 : W4;
    int nb = blockIdx.x * 32, kb = blockIdx.y * 32;
    tile[threadIdx.y][threadIdx.x] = W[(size_t)(kb + threadIdx.y) * HC + nb + threadIdx.x];
    __syncthreads();
    float x = tile[threadIdx.x][threadIdx.y];   // W[kb+tx][nb+ty]
    int n = nb + threadIdx.y, k = kb + threadIdx.x;
    Wt16[(size_t)z * HC * HC + (size_t)n * HC + k] = (_Float16)x;
}

// ---------------- GEMMs (fused with a_src/a_dst head dots) ----------------

// layer-1 K=5 GEMM + per-head attention dots
__global__ void gemm_k5(const float* __restrict__ x, const float* __restrict__ Wm,
                        const float* __restrict__ a_s, const float* __restrict__ a_d,
                        _Float16* __restrict__ out16,
                        float* __restrict__ a_srcB, float* __restrict__ a_dstB) {
    int n = blockIdx.x;
    int tid = threadIdx.x;
    __shared__ float xr[8];
    __shared__ float vrow[HC];
    if (tid < NF) xr[tid] = x[n * NF + tid];
    __syncthreads();
    float x0 = xr[0], x1 = xr[1], x2 = xr[2], x3 = xr[3], x4 = xr[4];
    for (int j = tid; j < HC; j += 256) {
        float v = x0 * Wm[j] + x1 * Wm[HC + j] + x2 * Wm[2 * HC + j]
                + x3 * Wm[3 * HC + j] + x4 * Wm[4 * HC + j];
        out16[(size_t)n * HC + j] = (_Float16)v;
        vrow[j] = v;
    }
    __syncthreads();
    int w = tid >> 6, lane = tid & 63;
#pragma unroll
    for (int q = 0; q < 2; ++q) {
        int h = w * 2 + q;
        float v0 = vrow[h * Cc + lane], v1 = vrow[h * Cc + 64 + lane];
        float s1 = v0 * a_s[h * Cc + lane] + v1 * a_s[h * Cc + 64 + lane];
        float s2 = v0 * a_d[h * Cc + lane] + v1 * a_d[h * Cc + 64 + lane];
#pragma unroll
        for (int off = 32; off; off >>= 1) {
            s1 += __shfl_xor(s1, off);
            s2 += __shfl_xor(s2, off);
        }
        if (lane == 0) { a_srcB[n * 8 + h] = s1; a_dstB[n * 8 + h] = s2; }
    }
}

// fp16 MFMA GEMM (r7 / m97 structure: quad-contiguous staging, [row][32] LDS)
// + fused per-head a_src/a_dst dots. blockIdx.x == head since BN == Cc == 128.
__global__ __launch_bounds__(256) void gemm_mfma(const _Float16* __restrict__ A,
                                                 const _Float16* __restrict__ Bt,
                                                 const float* __restrict__ a_s,
                                                 const float* __restrict__ a_d,
                                                 _Float16* __restrict__ C16,
                                                 float* __restrict__ a_srcB,
                                                 float* __restrict__ a_dstB) {
    __shared__ _Float16 As[128 * 32];
    __shared__ _Float16 Bs[128 * 32];
    __shared__ float ps[128][2];
    __shared__ float pd[128][2];
    int tid = threadIdx.x;
    int wave = tid >> 6, lane = tid & 63;
    int wr = wave >> 1, wc = wave & 1;
    int row0 = blockIdx.y * 128;
    int col0 = blockIdx.x * 128;
    int h = blockIdx.x;   // head

    f32x4 acc[4][4];
#pragma unroll
    for (int i = 0; i < 4; ++i)
#pragma unroll
        for (int j = 0; j < 4; ++j) acc[i][j] = (f32x4){0.f, 0.f, 0.f, 0.f};

    int srow = lane >> 2;          // quad covers 64 contiguous bytes of one row
    int scol = (lane & 3) * 8;
    int fr = lane & 15;
    int fk = (lane >> 4) * 8;

    for (int kb = 0; kb < 1024; kb += 32) {
#pragma unroll
        for (int cc = 0; cc < 2; ++cc) {
            int c = wave + cc * 4;
            int r = c * 16 + srow;
            gl_lds16(A + (size_t)(row0 + r) * 1024 + kb + scol, &As[c * 512 + lane * 8]);
            gl_lds16(Bt + (size_t)(col0 + r) * 1024 + kb + scol, &Bs[c * 512 + lane * 8]);
        }
        __syncthreads();

        half8 af[4], bf[4];
#pragma unroll
        for (int i = 0; i < 4; ++i)
            af[i] = *(const half8*)&As[(wr * 64 + i * 16 + fr) * 32 + fk];
#pragma unroll
        for (int j = 0; j < 4; ++j)
            bf[j] = *(const half8*)&Bs[(wc * 64 + j * 16 + fr) * 32 + fk];
#pragma unroll
        for (int i = 0; i < 4; ++i)
#pragma unroll
            for (int j = 0; j < 4; ++j)
                acc[i][j] = __builtin_amdgcn_mfma_f32_16x16x32_f16(af[i], bf[j], acc[i][j],
                                                                   0, 0, 0);
        __syncthreads();
    }

    int cn = lane & 15, rq = (lane >> 4) * 4;
    // C write
#pragma unroll
    for (int i = 0; i < 4; ++i) {
        int rbase = row0 + wr * 64 + i * 16 + rq;
#pragma unroll
        for (int j = 0; j < 4; ++j) {
            int col = col0 + wc * 64 + j * 16 + cn;
#pragma unroll
            for (int r = 0; r < 4; ++r) {
                int row = rbase + r;
                if (row < Nn) C16[(size_t)row * HC + col] = (_Float16)acc[i][j][r];
            }
        }
    }
    // fused a_src/a_dst dots over this head's 128 channels
    float asv[4], adv[4];
#pragma unroll
    for (int j = 0; j < 4; ++j) {
        int c = wc * 64 + j * 16 + cn;
        asv[j] = a_s[h * Cc + c];
        adv[j] = a_d[h * Cc + c];
    }
#pragma unroll
    for (int i = 0; i < 4; ++i)
#pragma unroll
        for (int r = 0; r < 4; ++r) {
            float rs = acc[i][0][r] * asv[0] + acc[i][1][r] * asv[1]
                     + acc[i][2][r] * asv[2] + acc[i][3][r] * asv[3];
            float rd = acc[i][0][r] * adv[0] + acc[i][1][r] * adv[1]
                     + acc[i][2][r] * adv[2] + acc[i][3][r] * adv[3];
#pragma unroll
            for (int off = 1; off < 16; off <<= 1) {
                rs += __shfl_xor(rs, off);
                rd += __shfl_xor(rd, off);
            }
            if (cn == 0) {
                int rib = wr * 64 + i * 16 + rq + r;
                ps[rib][wc] = rs;
                pd[rib][wc] = rd;
            }
        }
    __syncthreads();
    if (tid < 128) {
        int row = row0 + tid;
        if (row < Nn) {
            a_srcB[row * 8 + h] = ps[tid][0] + ps[tid][1];
            a_dstB[row * 8 + h] = pd[tid][0] + pd[tid][1];
        }
    }
}

// ---------------- fused attention aggregate (single pass, 4 waves/node) ----------------

// BLOCK = ONE NODE, 4 waves (r12 structure — measured best). Softmax shift = aself
// (exact per-node; Glorot-scale logits can't overflow fp32 exp). Each sub-wave gathers
// edges beg+sub::4 (4-unrolled => stride 16), accumulating UNNORMALIZED acc + denom s.
// Additive combine via LDS (r12 layout: conflicts present but fully latency-hidden —
// the "conflict-free" r14 variant measured SLOWER via worse codegen/occupancy).
// mode 0: out = elu(agg+bias) -> fp16 into A2 (next GEMM input)
// mode 1: head-mean+bias+elu, dot with lin_w -> dnode[n] (scalar)
__global__ __launch_bounds__(256) void aggregate_k(const _Float16* __restrict__ xl16,
                                                   const float4* __restrict__ eaP,
                                                   const float* __restrict__ loop_attr,
                                                   const float* __restrict__ a_srcB,
                                                   const float* __restrict__ a_dstB,
                                                   const float* __restrict__ w_ae,
                                                   const int* __restrict__ rowptr,
                                                   const float* __restrict__ bias,
                                                   const float* __restrict__ lin_w,
                                                   _Float16* __restrict__ A2,
                                                   float* __restrict__ dnode,
                                                   int raw_mode) {
    __shared__ float cmbA[3][1024];
    __shared__ float cmbS[3][64];
    int sub = threadIdx.x >> 6;
    int lane = threadIdx.x & 63;
    int n = blockIdx.x;
    int beg = rowptr[n], end = rowptr[n + 1];
    int hc = lane >> 3;     // this lane's head

    float w0c = w_ae[hc], w1c = w_ae[8 + hc], w2c = w_ae[16 + hc];
    float adst_n = a_dstB[n * 8 + hc];
    float asrc_n = a_srcB[n * 8 + hc];
    float f0 = loop_attr[n * 3 + 0], f1 = loop_attr[n * 3 + 1], f2 = loop_attr[n * 3 + 2];
    float av = asrc_n + adst_n + f0 * w0c + f1 * w1c + f2 * w2c;
    float aself = (av > 0.f) ? av : 0.2f * av;   // softmax shift; self weight = 1

    float acc[16];
    float s;
    int loff = lane * 16;
    if (sub == 0) {
        // self term (weight exp(0) = 1)
        const _Float16* r = xl16 + (size_t)n * HC + loff;
        half8 r0 = *(const half8*)r;
        half8 r1 = *(const half8*)(r + 8);
#pragma unroll
        for (int j = 0; j < 8; ++j) {
            acc[j] = (float)r0[j];
            acc[8 + j] = (float)r1[j];
        }
        s = 1.0f;
    } else {
#pragma unroll
        for (int j = 0; j < 16; ++j) acc[j] = 0.f;
        s = 0.0f;
    }

    for (int i0 = beg + sub; i0 < end; i0 += 16) {
        bool v1 = (i0 + 4 < end), v2 = (i0 + 8 < end), v3 = (i0 + 12 < end);
        int i1 = v1 ? i0 + 4 : i0;
        int i2 = v2 ? i0 + 8 : i0;
        int i3 = v3 ? i0 + 12 : i0;
        float4 e0 = eaP[i0], e1 = eaP[i1], e2 = eaP[i2], e3 = eaP[i3];
        int s0 = __float_as_int(e0.w), s1 = __float_as_int(e1.w);
        int s2 = __float_as_int(e2.w), s3 = __float_as_int(e3.w);
        float as0 = a_srcB[s0 * 8 + hc], as1 = a_srcB[s1 * 8 + hc];
        float as2 = a_srcB[s2 * 8 + hc], as3 = a_srcB[s3 * 8 + hc];
        const _Float16* p0 = xl16 + (size_t)s0 * HC + loff;
        const _Float16* p1 = xl16 + (size_t)s1 * HC + loff;
        const _Float16* p2 = xl16 + (size_t)s2 * HC + loff;
        const _Float16* p3 = xl16 + (size_t)s3 * HC + loff;
        half8 q0a = *(const half8*)p0, q0b = *(const half8*)(p0 + 8);
        half8 q1a = *(const half8*)p1, q1b = *(const half8*)(p1 + 8);
        half8 q2a = *(const half8*)p2, q2b = *(const half8*)(p2 + 8);
        half8 q3a = *(const half8*)p3, q3b = *(const half8*)(p3 + 8);
        float al0 = as0 + adst_n + e0.x * w0c + e0.y * w1c + e0.z * w2c;
        float al1 = as1 + adst_n + e1.x * w0c + e1.y * w1c + e1.z * w2c;
        float al2 = as2 + adst_n + e2.x * w0c + e2.y * w1c + e2.z * w2c;
        float al3 = as3 + adst_n + e3.x * w0c + e3.y * w1c + e3.z * w2c;
        al0 = (al0 > 0.f) ? al0 : 0.2f * al0;
        al1 = (al1 > 0.f) ? al1 : 0.2f * al1;
        al2 = (al2 > 0.f) ? al2 : 0.2f * al2;
        al3 = (al3 > 0.f) ? al3 : 0.2f * al3;
        float u0 = __expf(al0 - aself);
        float u1 = v1 ? __expf(al1 - aself) : 0.f;
        float u2 = v2 ? __expf(al2 - aself) : 0.f;
        float u3 = v3 ? __expf(al3 - aself) : 0.f;
        s += u0 + u1 + u2 + u3;
#pragma unroll
        for (int j = 0; j < 8; ++j) {
            float t0 = acc[j], t1 = acc[8 + j];
            t0 = fmaf(u0, (float)q0a[j], t0);  t1 = fmaf(u0, (float)q0b[j], t1);
            t0 = fmaf(u1, (float)q1a[j], t0);  t1 = fmaf(u1, (float)q1b[j], t1);
            t0 = fmaf(u2, (float)q2a[j], t0);  t1 = fmaf(u2, (float)q2b[j], t1);
            t0 = fmaf(u3, (float)q3a[j], t0);  t1 = fmaf(u3, (float)q3b[j], t1);
            acc[j] = t0; acc[8 + j] = t1;
        }
    }

    // additive combine across the 4 sub-waves
    if (sub != 0) {
#pragma unroll
        for (int j = 0; j < 4; ++j)
            *(float4*)&cmbA[sub - 1][loff + j * 4] = *(const float4*)&acc[j * 4];
        cmbS[sub - 1][lane] = s;
    }
    __syncthreads();
    if (sub != 0) return;

#pragma unroll
    for (int k = 0; k < 3; ++k) {
        s += cmbS[k][lane];
#pragma unroll
        for (int j = 0; j < 4; ++j) {
            float4 c4 = *(const float4*)&cmbA[k][loff + j * 4];
            acc[j * 4 + 0] += c4.x;
            acc[j * 4 + 1] += c4.y;
            acc[j * 4 + 2] += c4.z;
            acc[j * 4 + 3] += c4.w;
        }
    }
    float inv = 1.f / (s + 1e-16f);

    if (!raw_mode) {
        int ch = loff;
        half8 hv0, hv1;
#pragma unroll
        for (int j = 0; j < 8; ++j) {
            hv0[j] = (_Float16)elu_f(fmaf(acc[j], inv, bias[ch + j]));
            hv1[j] = (_Float16)elu_f(fmaf(acc[8 + j], inv, bias[ch + 8 + j]));
        }
        _Float16* p = A2 + (size_t)n * 1024 + ch;
        *(half8*)p = hv0;
        *(half8*)(p + 8) = hv1;
    } else {
        // normalize, then head-mean over the 8 lanes sharing lane&7
#pragma unroll
        for (int j = 0; j < 16; ++j) acc[j] *= inv;
#pragma unroll
        for (int off = 8; off < 64; off <<= 1)
#pragma unroll
            for (int j = 0; j < 16; ++j) acc[j] += __shfl_xor(acc[j], off);
        int c0 = (lane & 7) * 16;
        float partial = 0.f;
#pragma unroll
        for (int j = 0; j < 16; ++j) {
            float v = elu_f(acc[j] * 0.125f + bias[c0 + j]);
            partial = fmaf(v, lin_w[c0 + j], partial);
        }
#pragma unroll
        for (int off = 1; off < 8; off <<= 1) partial += __shfl_xor(partial, off);
        if (lane == 0) dnode[n] = partial;
    }
}

// ---------------- pooling: reduce per-node scalars per group ----------------

__global__ __launch_bounds__(256) void pool_final_k(const float* __restrict__ dnode,
                                                    const int* __restrict__ gstart,
                                                    const float* __restrict__ lin_b,
                                                    float* __restrict__ out) {
    __shared__ float sh[256];
    int g = blockIdx.x;
    int tid = threadIdx.x;
    int s = gstart[g], e = gstart[g + 1];
    float acc = 0.f;
    for (int n = s + tid; n < e; n += 256) acc += dnode[n];
    sh[tid] = acc;
    __syncthreads();
    for (int off = 128; off; off >>= 1) {
        if (tid < off) sh[tid] += sh[tid + off];
        __syncthreads();
    }
    if (tid == 0) out[g] = sh[0] / fmaxf((float)(e - s), 1.f) + lin_b[0];
}

// ---------------- launch ----------------

extern "C" void kernel_launch(void* const* d_in, const int* in_sizes, int n_in,
                              void* d_out, int out_size, void* d_ws, size_t ws_size,
                              hipStream_t stream) {
    const float* x = (const float*)d_in[0];
    const int* ei = (const int*)d_in[1];
    const float* ea = (const float*)d_in[2];
    const int* batch = (const int*)d_in[3];
    const float *Wl[4], *Wel[4], *asl[4], *adl[4], *ael[4], *bl[4];
    for (int l = 0; l < 4; ++l) {
        Wl[l] = (const float*)d_in[4 + 6 * l];
        Wel[l] = (const float*)d_in[5 + 6 * l];
        asl[l] = (const float*)d_in[6 + 6 * l];
        adl[l] = (const float*)d_in[7 + 6 * l];
        ael[l] = (const float*)d_in[8 + 6 * l];
        bl[l] = (const float*)d_in[9 + 6 * l];
    }
    const float* lin_w = (const float*)d_in[28];
    const float* lin_b = (const float*)d_in[29];
    const int* srcA = ei;
    const int* dstA = ei + En;

    float* Wp = (float*)d_ws;
    size_t o = 0;
    _Float16* A2 = (_Float16*)(Wp + o); o += (size_t)Mpad * 512;         // elu acts fp16
    _Float16* Wt16 = (_Float16*)(Wp + o); o += (size_t)3 * HC * HC / 2;  // 3 fp16 W^T
    _Float16* xl16 = (_Float16*)(Wp + o); o += (size_t)Nn * HC / 2;      // xl fp16
    float4* eaP = (float4*)(Wp + o); o += (size_t)En * 4;                // packed (ea,src)
    float* loop_attr = Wp + o; o += Nn * 3;
    int* cnt = (int*)(Wp + o); o += Nn;
    int* rowptr = (int*)(Wp + o); o += Nn + 1;
    int* fillptr = (int*)(Wp + o); o += Nn;
    int* gstart = (int*)(Wp + o); o += Gg + 1;
    float* a_srcB = Wp + o; o += Nn * Hh;
    float* a_dstB = Wp + o; o += Nn * Hh;
    float* w_ae_all = Wp + o; o += 128;
    float* dnode = Wp + o; o += Nn;

    hipMemsetAsync(cnt, 0, Nn * sizeof(int), stream);
    hipMemsetAsync(loop_attr, 0, Nn * 3 * sizeof(float), stream);

    deg_sum_k<<<(En + 255) / 256, 256, 0, stream>>>(dstA, ea, cnt, loop_attr);
    scan_k<<<1, 1024, 0, stream>>>(cnt, rowptr, fillptr, loop_attr, batch, gstart);
    csr_fill_k<<<(En + 255) / 256, 256, 0, stream>>>(srcA, dstA, ea, fillptr, eaP);
    wae_all_k<<<1, 128, 0, stream>>>(Wel[0], ael[0], Wel[1], ael[1], Wel[2], ael[2],
                                     Wel[3], ael[3], w_ae_all);
    wsplit_all_k<<<dim3(32, 32, 3), dim3(32, 32), 0, stream>>>(Wl[1], Wl[2], Wl[3], Wt16);

    for (int l = 0; l < 4; ++l) {
        if (l == 0)
            gemm_k5<<<Nn, 256, 0, stream>>>(x, Wl[0], asl[0], adl[0], xl16, a_srcB, a_dstB);
        else
            gemm_mfma<<<dim3(HC / 128, Mpad / 128), 256, 0, stream>>>(
                A2, Wt16 + (size_t)(l - 1) * HC * HC, asl[l], adl[l], xl16, a_srcB, a_dstB);
        aggregate_k<<<Nn, 256, 0, stream>>>(xl16, eaP, loop_attr, a_srcB,
                                            a_dstB, w_ae_all + l * 24, rowptr,
                                            bl[l], lin_w, A2, dnode,
                                            (l == 3) ? 1 : 0);
    }
    pool_final_k<<<Gg, 256, 0, stream>>>(dnode, gstart, lin_b, (float*)d_out);
}

// Round 16
// 554.918 us; speedup vs baseline: 1.1590x; 1.0162x over previous
//
#include <hip/hip_runtime.h>
#include <math.h>

#define Nn 10000
#define En 160000
#define NF 5
#define EF 3
#define Hh 8
#define Cc 128
#define HC 1024
#define Gg 16

#define Mpad 10112   // 79 * 128

typedef __attribute__((ext_vector_type(8))) _Float16 half8;
typedef __attribute__((ext_vector_type(4))) float f32x4;

// ---------------- helpers ----------------

__device__ __forceinline__ void gl_lds16(const void* g, void* l) {
    __builtin_amdgcn_global_load_lds((const __attribute__((address_space(1))) void*)g,
                                     (__attribute__((address_space(3))) void*)l, 16, 0, 0);
}

__device__ __forceinline__ float elu_f(float v) {
    return (v > 0.f) ? v : expm1f(v);
}

// ---------------- preprocessing ----------------

// count-only (1 atomic/edge; the 3 ea-sum atomics moved into csr_fill_k)
__global__ void deg_sum_k(const int* __restrict__ dst, int* __restrict__ cnt) {
    int e = blockIdx.x * 256 + threadIdx.x;
    if (e >= En) return;
    atomicAdd(&cnt[dst[e]], 1);
}

// scan (10 elems/thread + one block scan) + group bounds, fused (no division pass —
// aggregate derives 1/deg from rowptr deltas)
__global__ __launch_bounds__(1024) void scan_k(const int* __restrict__ cnt,
                                               int* __restrict__ rowptr,
                                               int* __restrict__ fillptr,
                                               const int* __restrict__ batch,
                                               int* __restrict__ gstart) {
    __shared__ int sh[1024];
    int tid = threadIdx.x;
    int base = tid * 10;
    int loc[10];
    int tsum = 0;
#pragma unroll
    for (int j = 0; j < 10; ++j) {
        int i = base + j;
        int v = (i < Nn) ? cnt[i] : 0;
        loc[j] = tsum;
        tsum += v;
    }
    sh[tid] = tsum;
    __syncthreads();
    for (int off = 1; off < 1024; off <<= 1) {
        int t = (tid >= off) ? sh[tid - off] : 0;
        __syncthreads();
        sh[tid] += t;
        __syncthreads();
    }
    int excl = sh[tid] - tsum;
#pragma unroll
    for (int j = 0; j < 10; ++j) {
        int i = base + j;
        if (i < Nn) {
            rowptr[i] = excl + loc[j];
            fillptr[i] = excl + loc[j];
        }
    }
    if (tid == 1023) rowptr[Nn] = sh[1023];
#pragma unroll
    for (int j = 0; j < 10; ++j) {
        int i = base + j;
        if (i < Nn) {
            int b = batch[i];
            if (i == 0) {
                for (int g = 0; g <= b; ++g) gstart[g] = 0;
            } else {
                int pb = batch[i - 1];
                for (int g = pb + 1; g <= b; ++g) gstart[g] = i;
            }
            if (i == Nn - 1) {
                for (int g = b + 1; g <= Gg; ++g) gstart[g] = Nn;
            }
        }
    }
}

// CSR fill: packed record (ea0,ea1,ea2,src-bits) + loop_attr raw-sum atomics
__global__ void csr_fill_k(const int* __restrict__ src, const int* __restrict__ dst,
                           const float* __restrict__ ea, int* __restrict__ fillptr,
                           float4* __restrict__ eaP, float* __restrict__ loop_attr) {
    int e = blockIdx.x * 256 + threadIdx.x;
    if (e >= En) return;
    int d = dst[e];
    float e0 = ea[e * 3 + 0], e1 = ea[e * 3 + 1], e2 = ea[e * 3 + 2];
    int pos = atomicAdd(&fillptr[d], 1);
    eaP[pos] = make_float4(e0, e1, e2, __int_as_float(src[e]));
    atomicAdd(&loop_attr[d * 3 + 0], e0);
    atomicAdd(&loop_attr[d * 3 + 1], e1);
    atomicAdd(&loop_attr[d * 3 + 2], e2);
}

// ---------------- weight prep (once, all layers) ----------------

__global__ void wae_all_k(const float* __restrict__ We1, const float* __restrict__ ae1,
                          const float* __restrict__ We2, const float* __restrict__ ae2,
                          const float* __restrict__ We3, const float* __restrict__ ae3,
                          const float* __restrict__ We4, const float* __restrict__ ae4,
                          float* __restrict__ w_ae_all) {
    int t = threadIdx.x;
    if (t >= 96) return;
    int l = t / 24, idx = t % 24;
    int f = idx >> 3, h = idx & 7;
    const float* We = (l == 0) ? We1 : (l == 1) ? We2 : (l == 2) ? We3 : We4;
    const float* ae = (l == 0) ? ae1 : (l == 1) ? ae2 : (l == 2) ? ae3 : ae4;
    float s = 0.f;
    for (int c = 0; c < Cc; ++c) s += We[f * HC + h * Cc + c] * ae[h * Cc + c];
    w_ae_all[l * 24 + f * 8 + h] = s;
}

__global__ __launch_bounds__(1024) void wsplit_all_k(const float* __restrict__ W2,
                                                     const float* __restrict__ W3,
                                                     const float* __restrict__ W4,
                                                     _Float16* __restrict__ Wt16) {
    __shared__ float tile[32][33];
    int z = blockIdx.z;
    const float* W = (z == 0) ? W2 : (z == 1) ? W3 : W4;
    int nb = blockIdx.x * 32, kb = blockIdx.y * 32;
    tile[threadIdx.y][threadIdx.x] = W[(size_t)(kb + threadIdx.y) * HC + nb + threadIdx.x];
    __syncthreads();
    float x = tile[threadIdx.x][threadIdx.y];   // W[kb+tx][nb+ty]
    int n = nb + threadIdx.y, k = kb + threadIdx.x;
    Wt16[(size_t)z * HC * HC + (size_t)n * HC + k] = (_Float16)x;
}

// ---------------- GEMMs (fused with a_src/a_dst head dots) ----------------

// layer-1 K=5 GEMM + per-head attention dots
__global__ void gemm_k5(const float* __restrict__ x, const float* __restrict__ Wm,
                        const float* __restrict__ a_s, const float* __restrict__ a_d,
                        _Float16* __restrict__ out16,
                        float* __restrict__ a_srcB, float* __restrict__ a_dstB) {
    int n = blockIdx.x;
    int tid = threadIdx.x;
    __shared__ float xr[8];
    __shared__ float vrow[HC];
    if (tid < NF) xr[tid] = x[n * NF + tid];
    __syncthreads();
    float x0 = xr[0], x1 = xr[1], x2 = xr[2], x3 = xr[3], x4 = xr[4];
    for (int j = tid; j < HC; j += 256) {
        float v = x0 * Wm[j] + x1 * Wm[HC + j] + x2 * Wm[2 * HC + j]
                + x3 * Wm[3 * HC + j] + x4 * Wm[4 * HC + j];
        out16[(size_t)n * HC + j] = (_Float16)v;
        vrow[j] = v;
    }
    __syncthreads();
    int w = tid >> 6, lane = tid & 63;
#pragma unroll
    for (int q = 0; q < 2; ++q) {
        int h = w * 2 + q;
        float v0 = vrow[h * Cc + lane], v1 = vrow[h * Cc + 64 + lane];
        float s1 = v0 * a_s[h * Cc + lane] + v1 * a_s[h * Cc + 64 + lane];
        float s2 = v0 * a_d[h * Cc + lane] + v1 * a_d[h * Cc + 64 + lane];
#pragma unroll
        for (int off = 32; off; off >>= 1) {
            s1 += __shfl_xor(s1, off);
            s2 += __shfl_xor(s2, off);
        }
        if (lane == 0) { a_srcB[n * 8 + h] = s1; a_dstB[n * 8 + h] = s2; }
    }
}

// fp16 MFMA GEMM (r7 / m97 structure: quad-contiguous staging, [row][32] LDS)
// + fused per-head a_src/a_dst dots. blockIdx.x == head since BN == Cc == 128.
__global__ __launch_bounds__(256) void gemm_mfma(const _Float16* __restrict__ A,
                                                 const _Float16* __restrict__ Bt,
                                                 const float* __restrict__ a_s,
                                                 const float* __restrict__ a_d,
                                                 _Float16* __restrict__ C16,
                                                 float* __restrict__ a_srcB,
                                                 float* __restrict__ a_dstB) {
    __shared__ _Float16 As[128 * 32];
    __shared__ _Float16 Bs[128 * 32];
    __shared__ float ps[128][2];
    __shared__ float pd[128][2];
    int tid = threadIdx.x;
    int wave = tid >> 6, lane = tid & 63;
    int wr = wave >> 1, wc = wave & 1;
    int row0 = blockIdx.y * 128;
    int col0 = blockIdx.x * 128;
    int h = blockIdx.x;   // head

    f32x4 acc[4][4];
#pragma unroll
    for (int i = 0; i < 4; ++i)
#pragma unroll
        for (int j = 0; j < 4; ++j) acc[i][j] = (f32x4){0.f, 0.f, 0.f, 0.f};

    int srow = lane >> 2;          // quad covers 64 contiguous bytes of one row
    int scol = (lane & 3) * 8;
    int fr = lane & 15;
    int fk = (lane >> 4) * 8;

    for (int kb = 0; kb < 1024; kb += 32) {
#pragma unroll
        for (int cc = 0; cc < 2; ++cc) {
            int c = wave + cc * 4;
            int r = c * 16 + srow;
            gl_lds16(A + (size_t)(row0 + r) * 1024 + kb + scol, &As[c * 512 + lane * 8]);
            gl_lds16(Bt + (size_t)(col0 + r) * 1024 + kb + scol, &Bs[c * 512 + lane * 8]);
        }
        __syncthreads();

        half8 af[4], bf[4];
#pragma unroll
        for (int i = 0; i < 4; ++i)
            af[i] = *(const half8*)&As[(wr * 64 + i * 16 + fr) * 32 + fk];
#pragma unroll
        for (int j = 0; j < 4; ++j)
            bf[j] = *(const half8*)&Bs[(wc * 64 + j * 16 + fr) * 32 + fk];
#pragma unroll
        for (int i = 0; i < 4; ++i)
#pragma unroll
            for (int j = 0; j < 4; ++j)
                acc[i][j] = __builtin_amdgcn_mfma_f32_16x16x32_f16(af[i], bf[j], acc[i][j],
                                                                   0, 0, 0);
        __syncthreads();
    }

    int cn = lane & 15, rq = (lane >> 4) * 4;
    // C write
#pragma unroll
    for (int i = 0; i < 4; ++i) {
        int rbase = row0 + wr * 64 + i * 16 + rq;
#pragma unroll
        for (int j = 0; j < 4; ++j) {
            int col = col0 + wc * 64 + j * 16 + cn;
#pragma unroll
            for (int r = 0; r < 4; ++r) {
                int row = rbase + r;
                if (row < Nn) C16[(size_t)row * HC + col] = (_Float16)acc[i][j][r];
            }
        }
    }
    // fused a_src/a_dst dots over this head's 128 channels
    float asv[4], adv[4];
#pragma unroll
    for (int j = 0; j < 4; ++j) {
        int c = wc * 64 + j * 16 + cn;
        asv[j] = a_s[h * Cc + c];
        adv[j] = a_d[h * Cc + c];
    }
#pragma unroll
    for (int i = 0; i < 4; ++i)
#pragma unroll
        for (int r = 0; r < 4; ++r) {
            float rs = acc[i][0][r] * asv[0] + acc[i][1][r] * asv[1]
                     + acc[i][2][r] * asv[2] + acc[i][3][r] * asv[3];
            float rd = acc[i][0][r] * adv[0] + acc[i][1][r] * adv[1]
                     + acc[i][2][r] * adv[2] + acc[i][3][r] * adv[3];
#pragma unroll
            for (int off = 1; off < 16; off <<= 1) {
                rs += __shfl_xor(rs, off);
                rd += __shfl_xor(rd, off);
            }
            if (cn == 0) {
                int rib = wr * 64 + i * 16 + rq + r;
                ps[rib][wc] = rs;
                pd[rib][wc] = rd;
            }
        }
    __syncthreads();
    if (tid < 128) {
        int row = row0 + tid;
        if (row < Nn) {
            a_srcB[row * 8 + h] = ps[tid][0] + ps[tid][1];
            a_dstB[row * 8 + h] = pd[tid][0] + pd[tid][1];
        }
    }
}

// ---------------- fused attention aggregate (single pass, 4 waves/node) ----------------

// BLOCK = ONE NODE, 4 waves (r12 structure — measured best). Softmax shift = aself.
// loop_attr now holds RAW sums; 1/deg derived from rowptr deltas (deg == cnt[n]).
// mode 0: out = elu(agg+bias) -> fp16 into A2 (next GEMM input)
// mode 1: head-mean+bias+elu, dot with lin_w -> dnode[n] (scalar)
__global__ __launch_bounds__(256) void aggregate_k(const _Float16* __restrict__ xl16,
                                                   const float4* __restrict__ eaP,
                                                   const float* __restrict__ loop_attr,
                                                   const float* __restrict__ a_srcB,
                                                   const float* __restrict__ a_dstB,
                                                   const float* __restrict__ w_ae,
                                                   const int* __restrict__ rowptr,
                                                   const float* __restrict__ bias,
                                                   const float* __restrict__ lin_w,
                                                   _Float16* __restrict__ A2,
                                                   float* __restrict__ dnode,
                                                   int raw_mode) {
    __shared__ float cmbA[3][1024];
    __shared__ float cmbS[3][64];
    int sub = threadIdx.x >> 6;
    int lane = threadIdx.x & 63;
    int n = blockIdx.x;
    int beg = rowptr[n], end = rowptr[n + 1];
    int hc = lane >> 3;     // this lane's head

    float w0c = w_ae[hc], w1c = w_ae[8 + hc], w2c = w_ae[16 + hc];
    float adst_n = a_dstB[n * 8 + hc];
    float asrc_n = a_srcB[n * 8 + hc];
    float invd = 1.0f / fmaxf((float)(end - beg), 1.0f);
    float f0 = loop_attr[n * 3 + 0] * invd;
    float f1 = loop_attr[n * 3 + 1] * invd;
    float f2 = loop_attr[n * 3 + 2] * invd;
    float av = asrc_n + adst_n + f0 * w0c + f1 * w1c + f2 * w2c;
    float aself = (av > 0.f) ? av : 0.2f * av;   // softmax shift; self weight = 1

    float acc[16];
    float s;
    int loff = lane * 16;
    if (sub == 0) {
        // self term (weight exp(0) = 1)
        const _Float16* r = xl16 + (size_t)n * HC + loff;
        half8 r0 = *(const half8*)r;
        half8 r1 = *(const half8*)(r + 8);
#pragma unroll
        for (int j = 0; j < 8; ++j) {
            acc[j] = (float)r0[j];
            acc[8 + j] = (float)r1[j];
        }
        s = 1.0f;
    } else {
#pragma unroll
        for (int j = 0; j < 16; ++j) acc[j] = 0.f;
        s = 0.0f;
    }

    for (int i0 = beg + sub; i0 < end; i0 += 16) {
        bool v1 = (i0 + 4 < end), v2 = (i0 + 8 < end), v3 = (i0 + 12 < end);
        int i1 = v1 ? i0 + 4 : i0;
        int i2 = v2 ? i0 + 8 : i0;
        int i3 = v3 ? i0 + 12 : i0;
        float4 e0 = eaP[i0], e1 = eaP[i1], e2 = eaP[i2], e3 = eaP[i3];
        int s0 = __float_as_int(e0.w), s1 = __float_as_int(e1.w);
        int s2 = __float_as_int(e2.w), s3 = __float_as_int(e3.w);
        float as0 = a_srcB[s0 * 8 + hc], as1 = a_srcB[s1 * 8 + hc];
        float as2 = a_srcB[s2 * 8 + hc], as3 = a_srcB[s3 * 8 + hc];
        const _Float16* p0 = xl16 + (size_t)s0 * HC + loff;
        const _Float16* p1 = xl16 + (size_t)s1 * HC + loff;
        const _Float16* p2 = xl16 + (size_t)s2 * HC + loff;
        const _Float16* p3 = xl16 + (size_t)s3 * HC + loff;
        half8 q0a = *(const half8*)p0, q0b = *(const half8*)(p0 + 8);
        half8 q1a = *(const half8*)p1, q1b = *(const half8*)(p1 + 8);
        half8 q2a = *(const half8*)p2, q2b = *(const half8*)(p2 + 8);
        half8 q3a = *(const half8*)p3, q3b = *(const half8*)(p3 + 8);
        float al0 = as0 + adst_n + e0.x * w0c + e0.y * w1c + e0.z * w2c;
        float al1 = as1 + adst_n + e1.x * w0c + e1.y * w1c + e1.z * w2c;
        float al2 = as2 + adst_n + e2.x * w0c + e2.y * w1c + e2.z * w2c;
        float al3 = as3 + adst_n + e3.x * w0c + e3.y * w1c + e3.z * w2c;
        al0 = (al0 > 0.f) ? al0 : 0.2f * al0;
        al1 = (al1 > 0.f) ? al1 : 0.2f * al1;
        al2 = (al2 > 0.f) ? al2 : 0.2f * al2;
        al3 = (al3 > 0.f) ? al3 : 0.2f * al3;
        float u0 = __expf(al0 - aself);
        float u1 = v1 ? __expf(al1 - aself) : 0.f;
        float u2 = v2 ? __expf(al2 - aself) : 0.f;
        float u3 = v3 ? __expf(al3 - aself) : 0.f;
        s += u0 + u1 + u2 + u3;
#pragma unroll
        for (int j = 0; j < 8; ++j) {
            float t0 = acc[j], t1 = acc[8 + j];
            t0 = fmaf(u0, (float)q0a[j], t0);  t1 = fmaf(u0, (float)q0b[j], t1);
            t0 = fmaf(u1, (float)q1a[j], t0);  t1 = fmaf(u1, (float)q1b[j], t1);
            t0 = fmaf(u2, (float)q2a[j], t0);  t1 = fmaf(u2, (float)q2b[j], t1);
            t0 = fmaf(u3, (float)q3a[j], t0);  t1 = fmaf(u3, (float)q3b[j], t1);
            acc[j] = t0; acc[8 + j] = t1;
        }
    }

    // additive combine across the 4 sub-waves
    if (sub != 0) {
#pragma unroll
        for (int j = 0; j < 4; ++j)
            *(float4*)&cmbA[sub - 1][loff + j * 4] = *(const float4*)&acc[j * 4];
        cmbS[sub - 1][lane] = s;
    }
    __syncthreads();
    if (sub != 0) return;

#pragma unroll
    for (int k = 0; k < 3; ++k) {
        s += cmbS[k][lane];
#pragma unroll
        for (int j = 0; j < 4; ++j) {
            float4 c4 = *(const float4*)&cmbA[k][loff + j * 4];
            acc[j * 4 + 0] += c4.x;
            acc[j * 4 + 1] += c4.y;
            acc[j * 4 + 2] += c4.z;
            acc[j * 4 + 3] += c4.w;
        }
    }
    float inv = 1.f / (s + 1e-16f);

    if (!raw_mode) {
        int ch = loff;
        half8 hv0, hv1;
#pragma unroll
        for (int j = 0; j < 8; ++j) {
            hv0[j] = (_Float16)elu_f(fmaf(acc[j], inv, bias[ch + j]));
            hv1[j] = (_Float16)elu_f(fmaf(acc[8 + j], inv, bias[ch + 8 + j]));
        }
        _Float16* p = A2 + (size_t)n * 1024 + ch;
        *(half8*)p = hv0;
        *(half8*)(p + 8) = hv1;
    } else {
        // normalize, then head-mean over the 8 lanes sharing lane&7
#pragma unroll
        for (int j = 0; j < 16; ++j) acc[j] *= inv;
#pragma unroll
        for (int off = 8; off < 64; off <<= 1)
#pragma unroll
            for (int j = 0; j < 16; ++j) acc[j] += __shfl_xor(acc[j], off);
        int c0 = (lane & 7) * 16;
        float partial = 0.f;
#pragma unroll
        for (int j = 0; j < 16; ++j) {
            float v = elu_f(acc[j] * 0.125f + bias[c0 + j]);
            partial = fmaf(v, lin_w[c0 + j], partial);
        }
#pragma unroll
        for (int off = 1; off < 8; off <<= 1) partial += __shfl_xor(partial, off);
        if (lane == 0) dnode[n] = partial;
    }
}

// ---------------- pooling: reduce per-node scalars per group ----------------

__global__ __launch_bounds__(256) void pool_final_k(const float* __restrict__ dnode,
                                                    const int* __restrict__ gstart,
                                                    const float* __restrict__ lin_b,
                                                    float* __restrict__ out) {
    __shared__ float sh[256];
    int g = blockIdx.x;
    int tid = threadIdx.x;
    int s = gstart[g], e = gstart[g + 1];
    float acc = 0.f;
    for (int n = s + tid; n < e; n += 256) acc += dnode[n];
    sh[tid] = acc;
    __syncthreads();
    for (int off = 128; off; off >>= 1) {
        if (tid < off) sh[tid] += sh[tid + off];
        __syncthreads();
    }
    if (tid == 0) out[g] = sh[0] / fmaxf((float)(e - s), 1.f) + lin_b[0];
}

// ---------------- launch ----------------

extern "C" void kernel_launch(void* const* d_in, const int* in_sizes, int n_in,
                              void* d_out, int out_size, void* d_ws, size_t ws_size,
                              hipStream_t stream) {
    const float* x = (const float*)d_in[0];
    const int* ei = (const int*)d_in[1];
    const float* ea = (const float*)d_in[2];
    const int* batch = (const int*)d_in[3];
    const float *Wl[4], *Wel[4], *asl[4], *adl[4], *ael[4], *bl[4];
    for (int l = 0; l < 4; ++l) {
        Wl[l] = (const float*)d_in[4 + 6 * l];
        Wel[l] = (const float*)d_in[5 + 6 * l];
        asl[l] = (const float*)d_in[6 + 6 * l];
        adl[l] = (const float*)d_in[7 + 6 * l];
        ael[l] = (const float*)d_in[8 + 6 * l];
        bl[l] = (const float*)d_in[9 + 6 * l];
    }
    const float* lin_w = (const float*)d_in[28];
    const float* lin_b = (const float*)d_in[29];
    const int* srcA = ei;
    const int* dstA = ei + En;

    float* Wp = (float*)d_ws;
    size_t o = 0;
    _Float16* A2 = (_Float16*)(Wp + o); o += (size_t)Mpad * 512;         // elu acts fp16
    _Float16* Wt16 = (_Float16*)(Wp + o); o += (size_t)3 * HC * HC / 2;  // 3 fp16 W^T
    _Float16* xl16 = (_Float16*)(Wp + o); o += (size_t)Nn * HC / 2;      // xl fp16
    float4* eaP = (float4*)(Wp + o); o += (size_t)En * 4;                // packed (ea,src)
    float* loop_attr = Wp + o; o += Nn * 3;                              // RAW ea sums
    int* cnt = (int*)(Wp + o); o += Nn;
    int* rowptr = (int*)(Wp + o); o += Nn + 1;
    int* fillptr = (int*)(Wp + o); o += Nn;
    int* gstart = (int*)(Wp + o); o += Gg + 1;
    float* a_srcB = Wp + o; o += Nn * Hh;
    float* a_dstB = Wp + o; o += Nn * Hh;
    float* w_ae_all = Wp + o; o += 128;
    float* dnode = Wp + o; o += Nn;

    hipMemsetAsync(cnt, 0, Nn * sizeof(int), stream);
    hipMemsetAsync(loop_attr, 0, Nn * 3 * sizeof(float), stream);

    deg_sum_k<<<(En + 255) / 256, 256, 0, stream>>>(dstA, cnt);
    scan_k<<<1, 1024, 0, stream>>>(cnt, rowptr, fillptr, batch, gstart);
    csr_fill_k<<<(En + 255) / 256, 256, 0, stream>>>(srcA, dstA, ea, fillptr, eaP,
                                                     loop_attr);
    wae_all_k<<<1, 128, 0, stream>>>(Wel[0], ael[0], Wel[1], ael[1], Wel[2], ael[2],
                                     Wel[3], ael[3], w_ae_all);
    wsplit_all_k<<<dim3(32, 32, 3), dim3(32, 32), 0, stream>>>(Wl[1], Wl[2], Wl[3], Wt16);

    for (int l = 0; l < 4; ++l) {
        if (l == 0)
            gemm_k5<<<Nn, 256, 0, stream>>>(x, Wl[0], asl[0], adl[0], xl16, a_srcB, a_dstB);
        else
            gemm_mfma<<<dim3(HC / 128, Mpad / 128), 256, 0, stream>>>(
                A2, Wt16 + (size_t)(l - 1) * HC * HC, asl[l], adl[l], xl16, a_srcB, a_dstB);
        aggregate_k<<<Nn, 256, 0, stream>>>(xl16, eaP, loop_attr, a_srcB,
                                            a_dstB, w_ae_all + l * 24, rowptr,
                                            bl[l], lin_w, A2, dnode,
                                            (l == 3) ? 1 : 0);
    }
    pool_final_k<<<Gg, 256, 0, stream>>>(dnode, gstart, lin_b, (float*)d_out);
}